// Round 14
// baseline (169.637 us; speedup 1.0000x reference)
//
#include <hip/hip_runtime.h>

#define N_NODES 50000
#define N_EDGES 800000
#define IN_C    256
#define HID_C   128
#define OUT_C   64

#define SCAN_CHUNK 512
#define SCAN_NB ((N_NODES + SCAN_CHUNK - 1) / SCAN_CHUNK)   // 98

#define NBK 391          // ceil(N_NODES/128) buckets of 128 nodes
#define PCH 2048         // edges per partition block
#define NPB ((N_EDGES + PCH - 1) / PCH)                      // 391

typedef __attribute__((ext_vector_type(8))) __bf16 bf16x8;
typedef __attribute__((ext_vector_type(4))) float f32x4;

// ----------------------------------------------------------- bf16 helpers --
__device__ __forceinline__ unsigned short f2bf(float f) {
    union { float f; unsigned int u; } c{f};
    unsigned int r = c.u + 0x7FFFu + ((c.u >> 16) & 1u);   // RNE
    return (unsigned short)(r >> 16);
}
__device__ __forceinline__ float bf2f(unsigned short b) {
    union { unsigned int u; float f; } c{(unsigned int)b << 16};
    return c.f;
}

// --------------------------------------------- degree + W bf16-transpose ---
__global__ void deg_kernel(const int* __restrict__ src,
                           const int* __restrict__ dst,
                           unsigned int* __restrict__ deg, int E,
                           const float* __restrict__ W1,
                           const float* __restrict__ W2,
                           unsigned short* __restrict__ Wt1,
                           unsigned short* __restrict__ Wt2) {
    const int bid = blockIdx.x;
    const int t   = threadIdx.x;
    if (Wt1 != nullptr && bid < 40) {
        if (bid < 32) {               // W1: 256x128
            int e = bid * 1024 + t * 4;
            float4 v = *(const float4*)&W1[e];
            int k = e >> 7, c = e & 127;
            Wt1[(c + 0) * IN_C + k] = f2bf(v.x);
            Wt1[(c + 1) * IN_C + k] = f2bf(v.y);
            Wt1[(c + 2) * IN_C + k] = f2bf(v.z);
            Wt1[(c + 3) * IN_C + k] = f2bf(v.w);
        } else {                      // W2: 128x64
            int e = (bid - 32) * 1024 + t * 4;
            float4 v = *(const float4*)&W2[e];
            int k = e >> 6, c = e & 63;
            Wt2[(c + 0) * HID_C + k] = f2bf(v.x);
            Wt2[(c + 1) * HID_C + k] = f2bf(v.y);
            Wt2[(c + 2) * HID_C + k] = f2bf(v.z);
            Wt2[(c + 3) * HID_C + k] = f2bf(v.w);
        }
    }
    int i = bid * blockDim.x + t;
    if (i < E) {
        int s = src[i];
        int d = dst[i];
        if ((unsigned)s < N_NODES && (unsigned)d < N_NODES)
            atomicAdd(&deg[d], 1u);
    }
}

// ------------------------------------------------------------------ scan ---
__global__ __launch_bounds__(256) void scan1_kernel(
        unsigned int* __restrict__ cur, unsigned int* __restrict__ bsum,
        float* __restrict__ dinv, int N) {
    __shared__ unsigned int lds[256];
    const int b = blockIdx.x;
    const int t = threadIdx.x;
    const int i0 = b * SCAN_CHUNK + 2 * t;

    unsigned e0 = (i0     < N) ? cur[i0]     : 0u;
    unsigned e1 = (i0 + 1 < N) ? cur[i0 + 1] : 0u;
    if (i0     < N) dinv[i0]     = rsqrtf((float)(e0 + 1u));
    if (i0 + 1 < N) dinv[i0 + 1] = rsqrtf((float)(e1 + 1u));

    unsigned p = e0 + e1;
    lds[t] = p;
    __syncthreads();
    for (int off = 1; off < 256; off <<= 1) {
        unsigned v = (t >= off) ? lds[t - off] : 0u;
        __syncthreads();
        lds[t] += v;
        __syncthreads();
    }
    unsigned excl = lds[t] - p;
    if (t == 255) bsum[b] = lds[255];
    if (i0     < N) cur[i0]     = excl;
    if (i0 + 1 < N) cur[i0 + 1] = excl + e0;
}

__global__ __launch_bounds__(256) void scan2_kernel(
        unsigned int* __restrict__ cur, const unsigned int* __restrict__ bsum,
        int N) {
    __shared__ unsigned int lds[256];
    const int b = blockIdx.x;
    const int t = threadIdx.x;
    lds[t] = (t < b && t < SCAN_NB) ? bsum[t] : 0u;
    __syncthreads();
    for (int off = 128; off > 0; off >>= 1) {
        if (t < off) lds[t] += lds[t + off];
        __syncthreads();
    }
    const unsigned offset = lds[0];
    const int i0 = b * SCAN_CHUNK + 2 * t;
    if (i0     < N) cur[i0]     += offset;
    if (i0 + 1 < N) cur[i0 + 1] += offset;
}

// ------------------------------------------------------------- bucket init -
__global__ void binit_kernel(const unsigned int* __restrict__ cur,
                             unsigned int* __restrict__ bcur,
                             unsigned int* __restrict__ bbase) {
    int t = threadIdx.x;
    if (t < NBK) {
        unsigned v = cur[t * 128];
        bcur[t]  = v;
        bbase[t] = v;
    }
    if (t == NBK) bbase[NBK] = N_EDGES;
}

// ----------------------------------------- fused gemm1 || edge partition ---
template <int KDIM, int NDIM>
__global__ __launch_bounds__(256) void fused_gemm_part_kernel(
        const float* __restrict__ A, const unsigned short* __restrict__ Wt,
        const float* __restrict__ dinv,
        unsigned short* __restrict__ Cout, int M,
        const int* __restrict__ src, const int* __restrict__ dst,
        unsigned int* __restrict__ bcur,
        unsigned int* __restrict__ gpairs, int E) {
    __shared__ union {
        struct { unsigned short A[64][40]; unsigned short B[NDIM][40]; } g;
        struct { unsigned int pairs[PCH];
                 unsigned int counts[512];
                 unsigned int starts[513];
                 unsigned int gbase[NBK];
                 unsigned int temp[256]; } p;
    } sh;

    const int bid  = blockIdx.x;
    const int t    = threadIdx.x;
    const int role = bid % 3;
    const int pb   = bid / 3;

    if (role == 2) {
        // --------------------------- partition -----------------------------
        const int base = pb * PCH;
        for (int i = t; i < 512; i += 256) sh.p.counts[i] = 0;
        __syncthreads();

        unsigned preg[PCH / 256], rreg[PCH / 256];
        bool val[PCH / 256];
#pragma unroll
        for (int j = 0; j < PCH / 256; ++j) {
            int i = base + j * 256 + t;
            val[j] = false;
            if (i < E) {
                int s = src[i], d = dst[i];
                if ((unsigned)s < N_NODES && (unsigned)d < N_NODES) {
                    val[j] = true;
                    unsigned bkt = (unsigned)d >> 7;
                    preg[j] = (bkt << 23) | (((unsigned)d & 127u) << 16) |
                              (unsigned)s;
                    rreg[j] = atomicAdd(&sh.p.counts[bkt], 1u);
                }
            }
        }
        __syncthreads();
        unsigned e0 = sh.p.counts[2 * t], e1 = sh.p.counts[2 * t + 1];
        unsigned pp = e0 + e1;
        sh.p.temp[t] = pp;
        __syncthreads();
        for (int off = 1; off < 256; off <<= 1) {
            unsigned v = (t >= off) ? sh.p.temp[t - off] : 0u;
            __syncthreads();
            sh.p.temp[t] += v;
            __syncthreads();
        }
        unsigned excl = sh.p.temp[t] - pp;
        sh.p.starts[2 * t]     = excl;
        sh.p.starts[2 * t + 1] = excl + e0;
        if (t == 255) sh.p.starts[512] = sh.p.temp[255];
        __syncthreads();
        for (int b = t; b < NBK; b += 256) {
            unsigned c = sh.p.counts[b];
            if (c) sh.p.gbase[b] = atomicAdd(&bcur[b], c);
        }
        __syncthreads();
#pragma unroll
        for (int j = 0; j < PCH / 256; ++j)
            if (val[j]) {
                unsigned bkt  = preg[j] >> 23;
                unsigned slot = sh.p.starts[bkt] + rreg[j];
                sh.p.pairs[slot] = preg[j];
            }
        __syncthreads();
        unsigned total = sh.p.starts[512];
        for (unsigned i = t; i < total; i += 256) {
            unsigned pd  = sh.p.pairs[i];
            unsigned bkt = pd >> 23;
            unsigned rank = i - sh.p.starts[bkt];
            gpairs[sh.p.gbase[bkt] + rank] = pd;
        }
        return;
    }

    // ------------------------------ gemm role ------------------------------
    const int gb = pb * 2 + role;
    if (gb >= (M + 63) / 64) return;
    constexpr int NF = NDIM / 16;
    const int block_row = gb * 64;
    const int w    = t >> 6;
    const int lane = t & 63;
    const int arow = lane & 15;
    const int g    = lane >> 4;

    f32x4 acc[NF] = {};

    for (int k0 = 0; k0 < KDIM; k0 += 32) {
#pragma unroll
        for (int q = 0; q < 2; ++q) {
            int u   = t * 2 + q;
            int row = u >> 3;
            int kq  = u & 7;
            int grow = block_row + row;
            if (grow >= M) grow = M - 1;
            float4 v = *(const float4*)&A[(size_t)grow * KDIM + k0 + kq * 4];
            ushort4 bb = {f2bf(v.x), f2bf(v.y), f2bf(v.z), f2bf(v.w)};
            *(ushort4*)&sh.g.A[row][kq * 4] = bb;
        }
        {
            constexpr int B8 = (NDIM * 4) / 256;   // uint4 units per thread
#pragma unroll
            for (int r = 0; r < B8; ++r) {
                int iu  = t * B8 + r;
                int col = iu >> 2;
                int k8  = iu & 3;
                *(uint4*)&sh.g.B[col][k8 * 8] =
                    *(const uint4*)&Wt[(size_t)col * KDIM + k0 + k8 * 8];
            }
        }
        __syncthreads();

        bf16x8 af = *(const bf16x8*)&sh.g.A[w * 16 + arow][g * 8];
#pragma unroll
        for (int f = 0; f < NF; ++f) {
            bf16x8 bf_ = *(const bf16x8*)&sh.g.B[f * 16 + arow][g * 8];
            acc[f] = __builtin_amdgcn_mfma_f32_16x16x32_bf16(af, bf_, acc[f],
                                                             0, 0, 0);
        }
        __syncthreads();
    }

#pragma unroll
    for (int i = 0; i < 4; ++i) {
        int row = block_row + w * 16 + g * 4 + i;
        if (row < M) {
            float dv = dinv[row];
#pragma unroll
            for (int f = 0; f < NF; ++f)
                Cout[(size_t)row * NDIM + f * 16 + arow] = f2bf(dv * acc[f][i]);
        }
    }
}

// ------------------------------------------------------------- fine fill ---
__global__ __launch_bounds__(256) void fine_fill_kernel(
        const unsigned int* __restrict__ gpairs,
        const unsigned int* __restrict__ bbase,
        unsigned int* __restrict__ cur,
        int* __restrict__ esrc, int N) {
    __shared__ unsigned int cnt[128];
    __shared__ unsigned int inc[128];
    const int b  = blockIdx.x;
    const int t  = threadIdx.x;
    const unsigned e0 = bbase[b], e1 = bbase[b + 1];
    const int node0 = b << 7;
    const int nn = min(128, N - node0);

    if (t < 128) cnt[t] = 0;
    __syncthreads();
    for (unsigned i = e0 + t; i < e1; i += 256) {
        unsigned dloc = (gpairs[i] >> 16) & 127u;
        atomicAdd(&cnt[dloc], 1u);
    }
    __syncthreads();
    if (t < 128) inc[t] = cnt[t];
    __syncthreads();
    for (int off = 1; off < 128; off <<= 1) {
        unsigned a = (t >= off && t < 128) ? inc[t - off] : 0u;
        __syncthreads();
        if (t < 128) inc[t] += a;
        __syncthreads();
    }
    if (t < 128) cnt[t] = inc[t] - cnt[t];
    __syncthreads();
    for (unsigned i = e0 + t; i < e1; i += 256) {
        unsigned pd   = gpairs[i];
        unsigned dloc = (pd >> 16) & 127u;
        unsigned r = atomicAdd(&cnt[dloc], 1u);
        esrc[e0 + r] = (int)(pd & 0xFFFFu);
    }
    __syncthreads();
    if (t < nn) cur[node0 + t] = e0 + inc[t];   // end(v)
}

// ------------------------------------- fused gather1 + GEMM2 (W2 in LDS) ---
// Per block: 8 nodes (32 lanes each). Phase 1: edge-gather of pre-scaled h1
// + b1 + ReLU -> f32 row in LDS. Phase 2: h2[v] = bf16(dinv_v * row @ W2).
// W2lds stride 132 bf16 (264B = 66 dwords, 66%32=2 -> 2-way banks, free).
template <int CIN, int COUT>
__global__ __launch_bounds__(256) void gather_gemm_kernel(
        const unsigned int* __restrict__ cur,   // ends
        const int* __restrict__ esrc,
        const float* __restrict__ dinv,
        const unsigned short* __restrict__ h,   // bf16, pre-scaled by dinv
        const float* __restrict__ bias1,
        const unsigned short* __restrict__ Wt2, // [COUT][CIN] bf16
        unsigned short* __restrict__ h2, int N) {
    constexpr int G    = CIN / 4;     // 32 lanes per node
    constexpr int NPB8 = 256 / G;     // 8 nodes per block
    constexpr int WSTR = CIN + 4;     // 132
    __shared__ unsigned short W2lds[COUT][WSTR];
    __shared__ float rows[NPB8][CIN];

    const int t = threadIdx.x;
    // stage W2 (uint2 = 4 bf16 units)
    {
        constexpr int UNITS = COUT * (CIN / 4);      // 2048
#pragma unroll
        for (int r = 0; r < UNITS / 256; ++r) {
            int u  = r * 256 + t;
            int c  = u / (CIN / 4);
            int kq = u % (CIN / 4);
            *(uint2*)&W2lds[c][kq * 4] =
                *(const uint2*)&Wt2[(size_t)c * CIN + kq * 4];
        }
    }

    const int n    = t / G;
    const int lane = t % G;
    const int v    = blockIdx.x * NPB8 + n;
    const bool valid = v < N;

    if (valid) {
        unsigned int start = (v == 0) ? 0u : cur[v - 1];
        unsigned int end   = cur[v];

        ushort4 hs = *(const ushort4*)&h[(size_t)v * CIN + lane * 4];
        float4 a0 = {bf2f(hs.x), bf2f(hs.y), bf2f(hs.z), bf2f(hs.w)};
        float4 a1 = {0.f, 0.f, 0.f, 0.f};
        float4 a2 = {0.f, 0.f, 0.f, 0.f};
        float4 a3 = {0.f, 0.f, 0.f, 0.f};

        unsigned int e = start;
        for (; e + 4 <= end; e += 4) {
            int s0 = esrc[e + 0];
            int s1 = esrc[e + 1];
            int s2 = esrc[e + 2];
            int s3 = esrc[e + 3];
            ushort4 v0 = *(const ushort4*)&h[(size_t)s0 * CIN + lane * 4];
            ushort4 v1 = *(const ushort4*)&h[(size_t)s1 * CIN + lane * 4];
            ushort4 v2 = *(const ushort4*)&h[(size_t)s2 * CIN + lane * 4];
            ushort4 v3 = *(const ushort4*)&h[(size_t)s3 * CIN + lane * 4];
            a0.x += bf2f(v0.x); a0.y += bf2f(v0.y); a0.z += bf2f(v0.z); a0.w += bf2f(v0.w);
            a1.x += bf2f(v1.x); a1.y += bf2f(v1.y); a1.z += bf2f(v1.z); a1.w += bf2f(v1.w);
            a2.x += bf2f(v2.x); a2.y += bf2f(v2.y); a2.z += bf2f(v2.z); a2.w += bf2f(v2.w);
            a3.x += bf2f(v3.x); a3.y += bf2f(v3.y); a3.z += bf2f(v3.z); a3.w += bf2f(v3.w);
        }
        for (; e < end; ++e) {
            int s = esrc[e];
            ushort4 v0 = *(const ushort4*)&h[(size_t)s * CIN + lane * 4];
            a0.x += bf2f(v0.x); a0.y += bf2f(v0.y); a0.z += bf2f(v0.z); a0.w += bf2f(v0.w);
        }
        float4 acc;
        acc.x = (a0.x + a1.x) + (a2.x + a3.x);
        acc.y = (a0.y + a1.y) + (a2.y + a3.y);
        acc.z = (a0.z + a1.z) + (a2.z + a3.z);
        acc.w = (a0.w + a1.w) + (a2.w + a3.w);

        float dv = dinv[v];
        float4 b = *(const float4*)&bias1[lane * 4];
        float4 r;
        r.x = fmaxf(fmaf(dv, acc.x, b.x), 0.f);
        r.y = fmaxf(fmaf(dv, acc.y, b.y), 0.f);
        r.z = fmaxf(fmaf(dv, acc.z, b.z), 0.f);
        r.w = fmaxf(fmaf(dv, acc.w, b.w), 0.f);
        *(float4*)&rows[n][lane * 4] = r;
    }
    __syncthreads();

    if (valid) {
        float dv = dinv[v];
#pragma unroll
        for (int cc = 0; cc < COUT / G; ++cc) {
            int c = lane + cc * G;
            float acc = 0.f;
#pragma unroll
            for (int k = 0; k < CIN; k += 8) {
                uint2 w0 = *(const uint2*)&W2lds[c][k];
                uint2 w1 = *(const uint2*)&W2lds[c][k + 4];
                float4 r0 = *(const float4*)&rows[n][k];
                float4 r1 = *(const float4*)&rows[n][k + 4];
                const unsigned short* wp0 = (const unsigned short*)&w0;
                const unsigned short* wp1 = (const unsigned short*)&w1;
                acc = fmaf(r0.x, bf2f(wp0[0]), acc);
                acc = fmaf(r0.y, bf2f(wp0[1]), acc);
                acc = fmaf(r0.z, bf2f(wp0[2]), acc);
                acc = fmaf(r0.w, bf2f(wp0[3]), acc);
                acc = fmaf(r1.x, bf2f(wp1[0]), acc);
                acc = fmaf(r1.y, bf2f(wp1[1]), acc);
                acc = fmaf(r1.z, bf2f(wp1[2]), acc);
                acc = fmaf(r1.w, bf2f(wp1[3]), acc);
            }
            h2[(size_t)v * COUT + c] = f2bf(dv * acc);
        }
    }
}

// ---------------------------------------------------------------- gather ---
// (layer 2: h2 pre-scaled; adds b2; fp32 out)
template <int C, bool RELU, bool OUTBF16>
__global__ __launch_bounds__(256) void gather_kernel(
        const unsigned int* __restrict__ cur,   // ends
        const int* __restrict__ esrc,
        const float* __restrict__ dinv,
        const unsigned short* __restrict__ h,   // bf16, pre-scaled by dinv
        const float* __restrict__ bias,
        void* __restrict__ out, int N) {
    constexpr int G = C / 4;
    int tid  = blockIdx.x * blockDim.x + threadIdx.x;
    int v    = tid / G;
    int lane = tid % G;
    if (v >= N) return;
    unsigned int start = (v == 0) ? 0u : cur[v - 1];
    unsigned int end   = cur[v];

    ushort4 hs = *(const ushort4*)&h[(size_t)v * C + lane * 4];
    float4 a0 = {bf2f(hs.x), bf2f(hs.y), bf2f(hs.z), bf2f(hs.w)};
    float4 a1 = {0.f, 0.f, 0.f, 0.f};
    float4 a2 = {0.f, 0.f, 0.f, 0.f};
    float4 a3 = {0.f, 0.f, 0.f, 0.f};

    unsigned int e = start;
    for (; e + 4 <= end; e += 4) {
        int s0 = esrc[e + 0];
        int s1 = esrc[e + 1];
        int s2 = esrc[e + 2];
        int s3 = esrc[e + 3];
        ushort4 v0 = *(const ushort4*)&h[(size_t)s0 * C + lane * 4];
        ushort4 v1 = *(const ushort4*)&h[(size_t)s1 * C + lane * 4];
        ushort4 v2 = *(const ushort4*)&h[(size_t)s2 * C + lane * 4];
        ushort4 v3 = *(const ushort4*)&h[(size_t)s3 * C + lane * 4];
        a0.x += bf2f(v0.x); a0.y += bf2f(v0.y); a0.z += bf2f(v0.z); a0.w += bf2f(v0.w);
        a1.x += bf2f(v1.x); a1.y += bf2f(v1.y); a1.z += bf2f(v1.z); a1.w += bf2f(v1.w);
        a2.x += bf2f(v2.x); a2.y += bf2f(v2.y); a2.z += bf2f(v2.z); a2.w += bf2f(v2.w);
        a3.x += bf2f(v3.x); a3.y += bf2f(v3.y); a3.z += bf2f(v3.z); a3.w += bf2f(v3.w);
    }
    for (; e < end; ++e) {
        int s = esrc[e];
        ushort4 v0 = *(const ushort4*)&h[(size_t)s * C + lane * 4];
        a0.x += bf2f(v0.x); a0.y += bf2f(v0.y); a0.z += bf2f(v0.z); a0.w += bf2f(v0.w);
    }
    float4 acc;
    acc.x = (a0.x + a1.x) + (a2.x + a3.x);
    acc.y = (a0.y + a1.y) + (a2.y + a3.y);
    acc.z = (a0.z + a1.z) + (a2.z + a3.z);
    acc.w = (a0.w + a1.w) + (a2.w + a3.w);

    float dv = dinv[v];
    float4 b = *(const float4*)&bias[lane * 4];
    float4 r;
    r.x = fmaf(dv, acc.x, b.x);
    r.y = fmaf(dv, acc.y, b.y);
    r.z = fmaf(dv, acc.z, b.z);
    r.w = fmaf(dv, acc.w, b.w);
    if (RELU) {
        r.x = fmaxf(r.x, 0.f);
        r.y = fmaxf(r.y, 0.f);
        r.z = fmaxf(r.z, 0.f);
        r.w = fmaxf(r.w, 0.f);
    }
    if (OUTBF16) {
        ushort4 o = {f2bf(r.x), f2bf(r.y), f2bf(r.z), f2bf(r.w)};
        *(ushort4*)&((unsigned short*)out)[(size_t)v * C + lane * 4] = o;
    } else {
        *(float4*)&((float*)out)[(size_t)v * C + lane * 4] = r;
    }
}

// ------------------------------------------- fallback path (atomics) ------
template <int C, int C4>
__global__ void scatter_kernel(const int* __restrict__ src,
                               const int* __restrict__ dst,
                               const float* __restrict__ dinv,
                               const float* __restrict__ h,
                               float* __restrict__ out, int E) {
    int tid  = blockIdx.x * blockDim.x + threadIdx.x;
    int e    = tid / C4;
    int lane = tid % C4;
    if (e >= E) return;
    int s = src[e];
    int d = dst[e];
    if ((unsigned)s >= N_NODES || (unsigned)d >= N_NODES) return;
    float norm = dinv[s] * dinv[d];
    float4 v = *(const float4*)&h[(size_t)s * C + lane * 4];
    float* o = &out[(size_t)d * C + lane * 4];
    unsafeAtomicAdd(o + 0, v.x * norm);
    unsafeAtomicAdd(o + 1, v.y * norm);
    unsafeAtomicAdd(o + 2, v.z * norm);
    unsafeAtomicAdd(o + 3, v.w * norm);
}

__global__ void dinv_only_kernel(const unsigned int* __restrict__ deg,
                                 float* __restrict__ dinv, int N) {
    int i = blockIdx.x * blockDim.x + threadIdx.x;
    if (i < N) dinv[i] = rsqrtf((float)(deg[i] + 1u));
}

template <int BM, int BN, int BK, int TM, int TN, int KDIM, int NDIM>
__global__ __launch_bounds__(256) void gemm_kernel(
        const float* __restrict__ A, const float* __restrict__ B,
        float* __restrict__ Cout, int M) {
    __shared__ float As[BK][BM + 1];
    __shared__ float Bs[BK][BN];

    constexpr int TX = BN / TN;
    const int t  = threadIdx.x;
    const int tx = t % TX;
    const int ty = t / TX;
    const int block_row = blockIdx.x * BM;
    const int col_base  = blockIdx.y * BN;

    float acc[TM][TN] = {};

    for (int k0 = 0; k0 < KDIM; k0 += BK) {
        for (int i = t; i < BM * BK / 4; i += 256) {
            int row = i / (BK / 4);
            int c4  = i % (BK / 4);
            int grow = block_row + row;
            if (grow >= M) grow = M - 1;
            float4 v = *(const float4*)&A[(size_t)grow * KDIM + k0 + c4 * 4];
            As[c4 * 4 + 0][row] = v.x;
            As[c4 * 4 + 1][row] = v.y;
            As[c4 * 4 + 2][row] = v.z;
            As[c4 * 4 + 3][row] = v.w;
        }
        for (int i = t; i < BK * BN / 4; i += 256) {
            int row = i / (BN / 4);
            int c4  = i % (BN / 4);
            *(float4*)&Bs[row][c4 * 4] =
                *(const float4*)&B[(size_t)(k0 + row) * NDIM + col_base + c4 * 4];
        }
        __syncthreads();

#pragma unroll
        for (int kk = 0; kk < BK; ++kk) {
            float4 av = *(const float4*)&As[kk][ty * TM];
            float a_[4] = {av.x, av.y, av.z, av.w};
            float4 bv[TN / 4];
#pragma unroll
            for (int j4 = 0; j4 < TN / 4; ++j4)
                bv[j4] = *(const float4*)&Bs[kk][tx * 4 + j4 * (BN / 2)];
#pragma unroll
            for (int i = 0; i < TM; ++i) {
                float ai = a_[i];
#pragma unroll
                for (int j4 = 0; j4 < TN / 4; ++j4) {
                    acc[i][j4 * 4 + 0] = fmaf(ai, bv[j4].x, acc[i][j4 * 4 + 0]);
                    acc[i][j4 * 4 + 1] = fmaf(ai, bv[j4].y, acc[i][j4 * 4 + 1]);
                    acc[i][j4 * 4 + 2] = fmaf(ai, bv[j4].z, acc[i][j4 * 4 + 2]);
                    acc[i][j4 * 4 + 3] = fmaf(ai, bv[j4].w, acc[i][j4 * 4 + 3]);
                }
            }
        }
        __syncthreads();
    }

#pragma unroll
    for (int i = 0; i < TM; ++i) {
        int grow = block_row + ty * TM + i;
        if (grow < M) {
#pragma unroll
            for (int j4 = 0; j4 < TN / 4; ++j4) {
                float4 v = {acc[i][j4 * 4 + 0], acc[i][j4 * 4 + 1],
                            acc[i][j4 * 4 + 2], acc[i][j4 * 4 + 3]};
                *(float4*)&Cout[(size_t)grow * NDIM + col_base + tx * 4 +
                                j4 * (BN / 2)] = v;
            }
        }
    }
}

template <int C, bool RELU>
__global__ void epilogue_kernel(const float* __restrict__ agg,
                                const float* __restrict__ h,
                                const float* __restrict__ dinv,
                                const float* __restrict__ bias,
                                float* __restrict__ out, int N) {
    int tid = blockIdx.x * blockDim.x + threadIdx.x;
    int total = N * (C / 4);
    if (tid >= total) return;
    int c4  = tid % (C / 4);
    int row = tid / (C / 4);
    float d2 = dinv[row];
    d2 *= d2;
    float4 a  = *(const float4*)&agg[(size_t)tid * 4];
    float4 hv = *(const float4*)&h[(size_t)tid * 4];
    float4 b  = *(const float4*)&bias[c4 * 4];
    float4 r;
    r.x = a.x + hv.x * d2 + b.x;
    r.y = a.y + hv.y * d2 + b.y;
    r.z = a.z + hv.z * d2 + b.z;
    r.w = a.w + hv.w * d2 + b.w;
    if (RELU) {
        r.x = fmaxf(r.x, 0.f);
        r.y = fmaxf(r.y, 0.f);
        r.z = fmaxf(r.z, 0.f);
        r.w = fmaxf(r.w, 0.f);
    }
    *(float4*)&out[(size_t)tid * 4] = r;
}

// ---------------------------------------------------------------- launch ---
extern "C" void kernel_launch(void* const* d_in, const int* in_sizes, int n_in,
                              void* d_out, int out_size, void* d_ws, size_t ws_size,
                              hipStream_t stream) {
    const float* x   = (const float*)d_in[0];
    const int*   ei  = (const int*)d_in[1];
    const float* W1  = (const float*)d_in[2];
    const float* b1  = (const float*)d_in[3];
    const float* W2  = (const float*)d_in[4];
    const float* b2  = (const float*)d_in[5];
    float*       out = (float*)d_out;

    const int* src = ei;
    const int* dst = ei + N_EDGES;

    char* ws = (char*)d_ws;
    size_t off = 0;
    auto alloc = [&](size_t bytes) {
        void* p = ws + off;
        off += (bytes + 255) & ~(size_t)255;
        return p;
    };

    // --- CSR-gather path layout ---
    unsigned int*   cur    = (unsigned int*)alloc(N_NODES * sizeof(unsigned int));
    unsigned int*   bsum   = (unsigned int*)alloc(SCAN_NB * sizeof(unsigned int));
    float*          dinv   = (float*)alloc(N_NODES * sizeof(float));
    int*            esrc   = (int*)alloc((size_t)N_EDGES * sizeof(int));
    unsigned int*   gpairs = (unsigned int*)alloc((size_t)N_EDGES * 4);
    unsigned int*   bbase  = (unsigned int*)alloc((NBK + 1) * sizeof(unsigned int));
    unsigned int*   bcur   = (unsigned int*)alloc(NBK * sizeof(unsigned int));
    unsigned short* Wt1    = (unsigned short*)alloc((size_t)IN_C * HID_C * 2);
    unsigned short* Wt2    = (unsigned short*)alloc((size_t)HID_C * OUT_C * 2);
    unsigned short* h1     = (unsigned short*)alloc((size_t)N_NODES * HID_C * 2);
    unsigned short* h2     = (unsigned short*)alloc((size_t)N_NODES * OUT_C * 2);
    size_t needed = off;

    if (ws_size >= needed) {
        hipMemsetAsync(cur, 0, N_NODES * sizeof(unsigned int), stream);

        deg_kernel<<<(N_EDGES + 255) / 256, 256, 0, stream>>>(
            src, dst, cur, N_EDGES, W1, W2, Wt1, Wt2);
        scan1_kernel<<<SCAN_NB, 256, 0, stream>>>(cur, bsum, dinv, N_NODES);
        scan2_kernel<<<SCAN_NB, 256, 0, stream>>>(cur, bsum, N_NODES);
        binit_kernel<<<1, 512, 0, stream>>>(cur, bcur, bbase);

        // fused: gemm1 (h1 = bf16(dinv*(x@W1))) || edge partition (packed)
        fused_gemm_part_kernel<IN_C, HID_C>
            <<<3 * NPB, 256, 0, stream>>>(x, Wt1, dinv, h1, N_NODES,
                                          src, dst, bcur, gpairs, N_EDGES);
        fine_fill_kernel<<<NBK, 256, 0, stream>>>(gpairs, bbase, cur, esrc,
                                                  N_NODES);
        // fused gather1 + GEMM2: h2 = bf16(dinv * (relu(...)@W2))
        {
            int blocks = (N_NODES + 7) / 8;
            gather_gemm_kernel<HID_C, OUT_C>
                <<<blocks, 256, 0, stream>>>(cur, esrc, dinv, h1, b1, Wt2,
                                             h2, N_NODES);
        }
        {
            int total = N_NODES * (OUT_C / 4);
            gather_kernel<OUT_C, false, false>
                <<<(total + 255) / 256, 256, 0, stream>>>(cur, esrc, dinv, h2,
                                                          b2, out, N_NODES);
        }
    } else {
        // ---------------- fallback: proven atomic-scatter path --------------
        off = 0;
        unsigned int* deg   = (unsigned int*)alloc(N_NODES * sizeof(unsigned int));
        float*        dinvF = (float*)alloc(N_NODES * sizeof(float));
        float*        h1F   = (float*)alloc((size_t)N_NODES * HID_C * sizeof(float));
        float*        agg1  = (float*)alloc((size_t)N_NODES * HID_C * sizeof(float));
        float*        h2F   = h1F;

        hipMemsetAsync(deg, 0, N_NODES * sizeof(unsigned int), stream);
        hipMemsetAsync(agg1, 0, (size_t)N_NODES * HID_C * sizeof(float), stream);
        hipMemsetAsync(out, 0, (size_t)N_NODES * OUT_C * sizeof(float), stream);

        deg_kernel<<<(N_EDGES + 255) / 256, 256, 0, stream>>>(
            src, dst, deg, N_EDGES, nullptr, nullptr, nullptr, nullptr);
        dinv_only_kernel<<<(N_NODES + 255) / 256, 256, 0, stream>>>(deg, dinvF,
                                                                    N_NODES);

        gemm_kernel<64, 64, 16, 4, 4, IN_C, HID_C>
            <<<dim3((N_NODES + 63) / 64, HID_C / 64), 256, 0, stream>>>(
                x, W1, h1F, N_NODES);
        {
            long long total = (long long)N_EDGES * (HID_C / 4);
            scatter_kernel<HID_C, HID_C / 4>
                <<<(unsigned)((total + 255) / 256), 256, 0, stream>>>(
                    src, dst, dinvF, h1F, agg1, N_EDGES);
        }
        {
            int total = N_NODES * (HID_C / 4);
            epilogue_kernel<HID_C, true>
                <<<(total + 255) / 256, 256, 0, stream>>>(agg1, h1F, dinvF, b1,
                                                          agg1, N_NODES);
        }
        gemm_kernel<64, 64, 16, 4, 4, HID_C, OUT_C>
            <<<dim3((N_NODES + 63) / 64, OUT_C / 64), 256, 0, stream>>>(
                agg1, W2, h2F, N_NODES);
        {
            long long total = (long long)N_EDGES * (OUT_C / 4);
            scatter_kernel<OUT_C, OUT_C / 4>
                <<<(unsigned)((total + 255) / 256), 256, 0, stream>>>(
                    src, dst, dinvF, h2F, out, N_EDGES);
        }
        {
            int total = N_NODES * (OUT_C / 4);
            epilogue_kernel<OUT_C, false>
                <<<(total + 255) / 256, 256, 0, stream>>>(out, h2F, dinvF, b2,
                                                          out, N_NODES);
        }
    }
}

// Round 15
// 147.661 us; speedup vs baseline: 1.1488x; 1.1488x over previous
//
#include <hip/hip_runtime.h>

#define N_NODES 50000
#define N_EDGES 800000
#define IN_C    256
#define HID_C   128
#define OUT_C   64

#define SCAN_CHUNK 512
#define SCAN_NB ((N_NODES + SCAN_CHUNK - 1) / SCAN_CHUNK)   // 98

#define NBK 391          // ceil(N_NODES/128) buckets of 128 nodes
#define PCH 2048         // edges per partition block
#define NPB ((N_EDGES + PCH - 1) / PCH)                      // 391

typedef __attribute__((ext_vector_type(8))) __bf16 bf16x8;
typedef __attribute__((ext_vector_type(4))) float f32x4;

// ----------------------------------------------------------- bf16 helpers --
__device__ __forceinline__ unsigned short f2bf(float f) {
    union { float f; unsigned int u; } c{f};
    unsigned int r = c.u + 0x7FFFu + ((c.u >> 16) & 1u);   // RNE
    return (unsigned short)(r >> 16);
}
__device__ __forceinline__ float bf2f(unsigned short b) {
    union { unsigned int u; float f; } c{(unsigned int)b << 16};
    return c.f;
}

// --------------------------------------------- degree + W bf16-transpose ---
__global__ void deg_kernel(const int* __restrict__ src,
                           const int* __restrict__ dst,
                           unsigned int* __restrict__ deg, int E,
                           const float* __restrict__ W1,
                           const float* __restrict__ W2,
                           unsigned short* __restrict__ Wt1,
                           unsigned short* __restrict__ Wt2) {
    const int bid = blockIdx.x;
    const int t   = threadIdx.x;
    if (Wt1 != nullptr && bid < 40) {
        if (bid < 32) {               // W1: 256x128
            int e = bid * 1024 + t * 4;
            float4 v = *(const float4*)&W1[e];
            int k = e >> 7, c = e & 127;
            Wt1[(c + 0) * IN_C + k] = f2bf(v.x);
            Wt1[(c + 1) * IN_C + k] = f2bf(v.y);
            Wt1[(c + 2) * IN_C + k] = f2bf(v.z);
            Wt1[(c + 3) * IN_C + k] = f2bf(v.w);
        } else {                      // W2: 128x64
            int e = (bid - 32) * 1024 + t * 4;
            float4 v = *(const float4*)&W2[e];
            int k = e >> 6, c = e & 63;
            Wt2[(c + 0) * HID_C + k] = f2bf(v.x);
            Wt2[(c + 1) * HID_C + k] = f2bf(v.y);
            Wt2[(c + 2) * HID_C + k] = f2bf(v.z);
            Wt2[(c + 3) * HID_C + k] = f2bf(v.w);
        }
    }
    int i = bid * blockDim.x + t;
    if (i < E) {
        int s = src[i];
        int d = dst[i];
        if ((unsigned)s < N_NODES && (unsigned)d < N_NODES)
            atomicAdd(&deg[d], 1u);
    }
}

// ------------------------------------------------------------------ scan ---
__global__ __launch_bounds__(256) void scan1_kernel(
        unsigned int* __restrict__ cur, unsigned int* __restrict__ bsum,
        float* __restrict__ dinv, int N) {
    __shared__ unsigned int lds[256];
    const int b = blockIdx.x;
    const int t = threadIdx.x;
    const int i0 = b * SCAN_CHUNK + 2 * t;

    unsigned e0 = (i0     < N) ? cur[i0]     : 0u;
    unsigned e1 = (i0 + 1 < N) ? cur[i0 + 1] : 0u;
    if (i0     < N) dinv[i0]     = rsqrtf((float)(e0 + 1u));
    if (i0 + 1 < N) dinv[i0 + 1] = rsqrtf((float)(e1 + 1u));

    unsigned p = e0 + e1;
    lds[t] = p;
    __syncthreads();
    for (int off = 1; off < 256; off <<= 1) {
        unsigned v = (t >= off) ? lds[t - off] : 0u;
        __syncthreads();
        lds[t] += v;
        __syncthreads();
    }
    unsigned excl = lds[t] - p;
    if (t == 255) bsum[b] = lds[255];
    if (i0     < N) cur[i0]     = excl;
    if (i0 + 1 < N) cur[i0 + 1] = excl + e0;
}

// scan2 now also emits bucket bases/cursors (binit fused; one less dispatch).
__global__ __launch_bounds__(256) void scan2_kernel(
        unsigned int* __restrict__ cur, const unsigned int* __restrict__ bsum,
        unsigned int* __restrict__ bcur, unsigned int* __restrict__ bbase,
        int N) {
    __shared__ unsigned int lds[256];
    const int b = blockIdx.x;
    const int t = threadIdx.x;
    lds[t] = (t < b && t < SCAN_NB) ? bsum[t] : 0u;
    __syncthreads();
    for (int off = 128; off > 0; off >>= 1) {
        if (t < off) lds[t] += lds[t + off];
        __syncthreads();
    }
    const unsigned offset = lds[0];
    const int i0 = b * SCAN_CHUNK + 2 * t;
    if (i0 < N) {
        unsigned v0 = cur[i0] + offset;
        cur[i0] = v0;
        if ((i0 & 127) == 0) {           // bucket boundary: snapshot start
            bcur[i0 >> 7]  = v0;
            bbase[i0 >> 7] = v0;
        }
    }
    if (i0 + 1 < N) cur[i0 + 1] += offset;
    if (b == 0 && t == 0) bbase[NBK] = N_EDGES;
}

// ----------------------------------------- fused gemm1 || edge partition ---
template <int KDIM, int NDIM>
__global__ __launch_bounds__(256) void fused_gemm_part_kernel(
        const float* __restrict__ A, const unsigned short* __restrict__ Wt,
        const float* __restrict__ dinv,
        unsigned short* __restrict__ Cout, int M,
        const int* __restrict__ src, const int* __restrict__ dst,
        unsigned int* __restrict__ bcur,
        unsigned int* __restrict__ gpairs, int E) {
    __shared__ union {
        struct { unsigned short A[64][40]; unsigned short B[NDIM][40]; } g;
        struct { unsigned int pairs[PCH];
                 unsigned int counts[512];
                 unsigned int starts[513];
                 unsigned int gbase[NBK];
                 unsigned int temp[256]; } p;
    } sh;

    const int bid  = blockIdx.x;
    const int t    = threadIdx.x;
    const int role = bid % 3;
    const int pb   = bid / 3;

    if (role == 2) {
        // --------------------------- partition -----------------------------
        const int base = pb * PCH;
        for (int i = t; i < 512; i += 256) sh.p.counts[i] = 0;
        __syncthreads();

        unsigned preg[PCH / 256], rreg[PCH / 256];
        bool val[PCH / 256];
#pragma unroll
        for (int j = 0; j < PCH / 256; ++j) {
            int i = base + j * 256 + t;
            val[j] = false;
            if (i < E) {
                int s = src[i], d = dst[i];
                if ((unsigned)s < N_NODES && (unsigned)d < N_NODES) {
                    val[j] = true;
                    unsigned bkt = (unsigned)d >> 7;
                    preg[j] = (bkt << 23) | (((unsigned)d & 127u) << 16) |
                              (unsigned)s;
                    rreg[j] = atomicAdd(&sh.p.counts[bkt], 1u);
                }
            }
        }
        __syncthreads();
        unsigned e0 = sh.p.counts[2 * t], e1 = sh.p.counts[2 * t + 1];
        unsigned pp = e0 + e1;
        sh.p.temp[t] = pp;
        __syncthreads();
        for (int off = 1; off < 256; off <<= 1) {
            unsigned v = (t >= off) ? sh.p.temp[t - off] : 0u;
            __syncthreads();
            sh.p.temp[t] += v;
            __syncthreads();
        }
        unsigned excl = sh.p.temp[t] - pp;
        sh.p.starts[2 * t]     = excl;
        sh.p.starts[2 * t + 1] = excl + e0;
        if (t == 255) sh.p.starts[512] = sh.p.temp[255];
        __syncthreads();
        for (int b = t; b < NBK; b += 256) {
            unsigned c = sh.p.counts[b];
            if (c) sh.p.gbase[b] = atomicAdd(&bcur[b], c);
        }
        __syncthreads();
#pragma unroll
        for (int j = 0; j < PCH / 256; ++j)
            if (val[j]) {
                unsigned bkt  = preg[j] >> 23;
                unsigned slot = sh.p.starts[bkt] + rreg[j];
                sh.p.pairs[slot] = preg[j];
            }
        __syncthreads();
        unsigned total = sh.p.starts[512];
        for (unsigned i = t; i < total; i += 256) {
            unsigned pd  = sh.p.pairs[i];
            unsigned bkt = pd >> 23;
            unsigned rank = i - sh.p.starts[bkt];
            gpairs[sh.p.gbase[bkt] + rank] = pd;
        }
        return;
    }

    // ------------------------------ gemm role ------------------------------
    const int gb = pb * 2 + role;
    if (gb >= (M + 63) / 64) return;
    constexpr int NF = NDIM / 16;
    const int block_row = gb * 64;
    const int w    = t >> 6;
    const int lane = t & 63;
    const int arow = lane & 15;
    const int g    = lane >> 4;

    f32x4 acc[NF] = {};

    for (int k0 = 0; k0 < KDIM; k0 += 32) {
#pragma unroll
        for (int q = 0; q < 2; ++q) {
            int u   = t * 2 + q;
            int row = u >> 3;
            int kq  = u & 7;
            int grow = block_row + row;
            if (grow >= M) grow = M - 1;
            float4 v = *(const float4*)&A[(size_t)grow * KDIM + k0 + kq * 4];
            ushort4 bb = {f2bf(v.x), f2bf(v.y), f2bf(v.z), f2bf(v.w)};
            *(ushort4*)&sh.g.A[row][kq * 4] = bb;
        }
        {
            constexpr int B8 = (NDIM * 4) / 256;   // uint4 units per thread
#pragma unroll
            for (int r = 0; r < B8; ++r) {
                int iu  = t * B8 + r;
                int col = iu >> 2;
                int k8  = iu & 3;
                *(uint4*)&sh.g.B[col][k8 * 8] =
                    *(const uint4*)&Wt[(size_t)col * KDIM + k0 + k8 * 8];
            }
        }
        __syncthreads();

        bf16x8 af = *(const bf16x8*)&sh.g.A[w * 16 + arow][g * 8];
#pragma unroll
        for (int f = 0; f < NF; ++f) {
            bf16x8 bf_ = *(const bf16x8*)&sh.g.B[f * 16 + arow][g * 8];
            acc[f] = __builtin_amdgcn_mfma_f32_16x16x32_bf16(af, bf_, acc[f],
                                                             0, 0, 0);
        }
        __syncthreads();
    }

#pragma unroll
    for (int i = 0; i < 4; ++i) {
        int row = block_row + w * 16 + g * 4 + i;
        if (row < M) {
            float dv = dinv[row];
#pragma unroll
            for (int f = 0; f < NF; ++f)
                Cout[(size_t)row * NDIM + f * 16 + arow] = f2bf(dv * acc[f][i]);
        }
    }
}

// ------------------------------------------------------------- fine fill ---
__global__ __launch_bounds__(256) void fine_fill_kernel(
        const unsigned int* __restrict__ gpairs,
        const unsigned int* __restrict__ bbase,
        unsigned int* __restrict__ cur,
        int* __restrict__ esrc, int N) {
    __shared__ unsigned int cnt[128];
    __shared__ unsigned int inc[128];
    const int b  = blockIdx.x;
    const int t  = threadIdx.x;
    const unsigned e0 = bbase[b], e1 = bbase[b + 1];
    const int node0 = b << 7;
    const int nn = min(128, N - node0);

    if (t < 128) cnt[t] = 0;
    __syncthreads();
    for (unsigned i = e0 + t; i < e1; i += 256) {
        unsigned dloc = (gpairs[i] >> 16) & 127u;
        atomicAdd(&cnt[dloc], 1u);
    }
    __syncthreads();
    if (t < 128) inc[t] = cnt[t];
    __syncthreads();
    for (int off = 1; off < 128; off <<= 1) {
        unsigned a = (t >= off && t < 128) ? inc[t - off] : 0u;
        __syncthreads();
        if (t < 128) inc[t] += a;
        __syncthreads();
    }
    if (t < 128) cnt[t] = inc[t] - cnt[t];
    __syncthreads();
    for (unsigned i = e0 + t; i < e1; i += 256) {
        unsigned pd   = gpairs[i];
        unsigned dloc = (pd >> 16) & 127u;
        unsigned r = atomicAdd(&cnt[dloc], 1u);
        esrc[e0 + r] = (int)(pd & 0xFFFFu);
    }
    __syncthreads();
    if (t < nn) cur[node0 + t] = e0 + inc[t];   // end(v)
}

// ------------------------------------------------ standalone MFMA GEMM -----
// ABF16: A already bf16 (uint4 copy staging). Output bf16(dinv*(A@W)).
template <int KDIM, int NDIM, bool ABF16>
__global__ __launch_bounds__(256) void mfma_gemm_kernel(
        const void* __restrict__ Ain, const unsigned short* __restrict__ Wt,
        const float* __restrict__ dinv,
        unsigned short* __restrict__ Cout, int M) {
    __shared__ unsigned short Alds[64][40];
    __shared__ unsigned short Blds[NDIM][40];

    const int t = threadIdx.x;
    constexpr int NF = NDIM / 16;
    const int block_row = blockIdx.x * 64;
    const int w    = t >> 6;
    const int lane = t & 63;
    const int arow = lane & 15;
    const int g    = lane >> 4;

    f32x4 acc[NF] = {};

    for (int k0 = 0; k0 < KDIM; k0 += 32) {
        if (ABF16) {
            const unsigned short* A = (const unsigned short*)Ain;
            int row = t >> 2;
            int k8  = t & 3;
            int grow = block_row + row;
            if (grow >= M) grow = M - 1;
            *(uint4*)&Alds[row][k8 * 8] =
                *(const uint4*)&A[(size_t)grow * KDIM + k0 + k8 * 8];
        } else {
            const float* A = (const float*)Ain;
#pragma unroll
            for (int q = 0; q < 2; ++q) {
                int u   = t * 2 + q;
                int row = u >> 3;
                int kq  = u & 7;
                int grow = block_row + row;
                if (grow >= M) grow = M - 1;
                float4 v = *(const float4*)&A[(size_t)grow * KDIM + k0 + kq * 4];
                ushort4 bb = {f2bf(v.x), f2bf(v.y), f2bf(v.z), f2bf(v.w)};
                *(ushort4*)&Alds[row][kq * 4] = bb;
            }
        }
        {
            constexpr int B8 = (NDIM * 4) / 256;
#pragma unroll
            for (int r = 0; r < B8; ++r) {
                int iu  = t * B8 + r;
                int col = iu >> 2;
                int k8  = iu & 3;
                *(uint4*)&Blds[col][k8 * 8] =
                    *(const uint4*)&Wt[(size_t)col * KDIM + k0 + k8 * 8];
            }
        }
        __syncthreads();

        bf16x8 af = *(const bf16x8*)&Alds[w * 16 + arow][g * 8];
#pragma unroll
        for (int f = 0; f < NF; ++f) {
            bf16x8 bf_ = *(const bf16x8*)&Blds[f * 16 + arow][g * 8];
            acc[f] = __builtin_amdgcn_mfma_f32_16x16x32_bf16(af, bf_, acc[f],
                                                             0, 0, 0);
        }
        __syncthreads();
    }

#pragma unroll
    for (int i = 0; i < 4; ++i) {
        int row = block_row + w * 16 + g * 4 + i;
        if (row < M) {
            float dv = dinv[row];
#pragma unroll
            for (int f = 0; f < NF; ++f)
                Cout[(size_t)row * NDIM + f * 16 + arow] = f2bf(dv * acc[f][i]);
        }
    }
}

// ---------------------------------------------------------------- gather ---
// h pre-scaled by dinv.  out[v] = dinv[v]*(sum h[s] + h[v]) + bias (+ReLU).
template <int C, bool RELU, bool OUTBF16>
__global__ __launch_bounds__(256) void gather_kernel(
        const unsigned int* __restrict__ cur,   // ends
        const int* __restrict__ esrc,
        const float* __restrict__ dinv,
        const unsigned short* __restrict__ h,   // bf16, pre-scaled by dinv
        const float* __restrict__ bias,
        void* __restrict__ out, int N) {
    constexpr int G = C / 4;
    int tid  = blockIdx.x * blockDim.x + threadIdx.x;
    int v    = tid / G;
    int lane = tid % G;
    if (v >= N) return;
    unsigned int start = (v == 0) ? 0u : cur[v - 1];
    unsigned int end   = cur[v];

    ushort4 hs = *(const ushort4*)&h[(size_t)v * C + lane * 4];
    float4 a0 = {bf2f(hs.x), bf2f(hs.y), bf2f(hs.z), bf2f(hs.w)};
    float4 a1 = {0.f, 0.f, 0.f, 0.f};
    float4 a2 = {0.f, 0.f, 0.f, 0.f};
    float4 a3 = {0.f, 0.f, 0.f, 0.f};

    unsigned int e = start;
    for (; e + 4 <= end; e += 4) {
        int s0 = esrc[e + 0];
        int s1 = esrc[e + 1];
        int s2 = esrc[e + 2];
        int s3 = esrc[e + 3];
        ushort4 v0 = *(const ushort4*)&h[(size_t)s0 * C + lane * 4];
        ushort4 v1 = *(const ushort4*)&h[(size_t)s1 * C + lane * 4];
        ushort4 v2 = *(const ushort4*)&h[(size_t)s2 * C + lane * 4];
        ushort4 v3 = *(const ushort4*)&h[(size_t)s3 * C + lane * 4];
        a0.x += bf2f(v0.x); a0.y += bf2f(v0.y); a0.z += bf2f(v0.z); a0.w += bf2f(v0.w);
        a1.x += bf2f(v1.x); a1.y += bf2f(v1.y); a1.z += bf2f(v1.z); a1.w += bf2f(v1.w);
        a2.x += bf2f(v2.x); a2.y += bf2f(v2.y); a2.z += bf2f(v2.z); a2.w += bf2f(v2.w);
        a3.x += bf2f(v3.x); a3.y += bf2f(v3.y); a3.z += bf2f(v3.z); a3.w += bf2f(v3.w);
    }
    for (; e < end; ++e) {
        int s = esrc[e];
        ushort4 v0 = *(const ushort4*)&h[(size_t)s * C + lane * 4];
        a0.x += bf2f(v0.x); a0.y += bf2f(v0.y); a0.z += bf2f(v0.z); a0.w += bf2f(v0.w);
    }
    float4 acc;
    acc.x = (a0.x + a1.x) + (a2.x + a3.x);
    acc.y = (a0.y + a1.y) + (a2.y + a3.y);
    acc.z = (a0.z + a1.z) + (a2.z + a3.z);
    acc.w = (a0.w + a1.w) + (a2.w + a3.w);

    float dv = dinv[v];
    float4 b = *(const float4*)&bias[lane * 4];
    float4 r;
    r.x = fmaf(dv, acc.x, b.x);
    r.y = fmaf(dv, acc.y, b.y);
    r.z = fmaf(dv, acc.z, b.z);
    r.w = fmaf(dv, acc.w, b.w);
    if (RELU) {
        r.x = fmaxf(r.x, 0.f);
        r.y = fmaxf(r.y, 0.f);
        r.z = fmaxf(r.z, 0.f);
        r.w = fmaxf(r.w, 0.f);
    }
    if (OUTBF16) {
        ushort4 o = {f2bf(r.x), f2bf(r.y), f2bf(r.z), f2bf(r.w)};
        *(ushort4*)&((unsigned short*)out)[(size_t)v * C + lane * 4] = o;
    } else {
        *(float4*)&((float*)out)[(size_t)v * C + lane * 4] = r;
    }
}

// ------------------------------------------- fallback path (atomics) ------
template <int C, int C4>
__global__ void scatter_kernel(const int* __restrict__ src,
                               const int* __restrict__ dst,
                               const float* __restrict__ dinv,
                               const float* __restrict__ h,
                               float* __restrict__ out, int E) {
    int tid  = blockIdx.x * blockDim.x + threadIdx.x;
    int e    = tid / C4;
    int lane = tid % C4;
    if (e >= E) return;
    int s = src[e];
    int d = dst[e];
    if ((unsigned)s >= N_NODES || (unsigned)d >= N_NODES) return;
    float norm = dinv[s] * dinv[d];
    float4 v = *(const float4*)&h[(size_t)s * C + lane * 4];
    float* o = &out[(size_t)d * C + lane * 4];
    unsafeAtomicAdd(o + 0, v.x * norm);
    unsafeAtomicAdd(o + 1, v.y * norm);
    unsafeAtomicAdd(o + 2, v.z * norm);
    unsafeAtomicAdd(o + 3, v.w * norm);
}

__global__ void dinv_only_kernel(const unsigned int* __restrict__ deg,
                                 float* __restrict__ dinv, int N) {
    int i = blockIdx.x * blockDim.x + threadIdx.x;
    if (i < N) dinv[i] = rsqrtf((float)(deg[i] + 1u));
}

template <int BM, int BN, int BK, int TM, int TN, int KDIM, int NDIM>
__global__ __launch_bounds__(256) void gemm_kernel(
        const float* __restrict__ A, const float* __restrict__ B,
        float* __restrict__ Cout, int M) {
    __shared__ float As[BK][BM + 1];
    __shared__ float Bs[BK][BN];

    constexpr int TX = BN / TN;
    const int t  = threadIdx.x;
    const int tx = t % TX;
    const int ty = t / TX;
    const int block_row = blockIdx.x * BM;
    const int col_base  = blockIdx.y * BN;

    float acc[TM][TN] = {};

    for (int k0 = 0; k0 < KDIM; k0 += BK) {
        for (int i = t; i < BM * BK / 4; i += 256) {
            int row = i / (BK / 4);
            int c4  = i % (BK / 4);
            int grow = block_row + row;
            if (grow >= M) grow = M - 1;
            float4 v = *(const float4*)&A[(size_t)grow * KDIM + k0 + c4 * 4];
            As[c4 * 4 + 0][row] = v.x;
            As[c4 * 4 + 1][row] = v.y;
            As[c4 * 4 + 2][row] = v.z;
            As[c4 * 4 + 3][row] = v.w;
        }
        for (int i = t; i < BK * BN / 4; i += 256) {
            int row = i / (BN / 4);
            int c4  = i % (BN / 4);
            *(float4*)&Bs[row][c4 * 4] =
                *(const float4*)&B[(size_t)(k0 + row) * NDIM + col_base + c4 * 4];
        }
        __syncthreads();

#pragma unroll
        for (int kk = 0; kk < BK; ++kk) {
            float4 av = *(const float4*)&As[kk][ty * TM];
            float a_[4] = {av.x, av.y, av.z, av.w};
            float4 bv[TN / 4];
#pragma unroll
            for (int j4 = 0; j4 < TN / 4; ++j4)
                bv[j4] = *(const float4*)&Bs[kk][tx * 4 + j4 * (BN / 2)];
#pragma unroll
            for (int i = 0; i < TM; ++i) {
                float ai = a_[i];
#pragma unroll
                for (int j4 = 0; j4 < TN / 4; ++j4) {
                    acc[i][j4 * 4 + 0] = fmaf(ai, bv[j4].x, acc[i][j4 * 4 + 0]);
                    acc[i][j4 * 4 + 1] = fmaf(ai, bv[j4].y, acc[i][j4 * 4 + 1]);
                    acc[i][j4 * 4 + 2] = fmaf(ai, bv[j4].z, acc[i][j4 * 4 + 2]);
                    acc[i][j4 * 4 + 3] = fmaf(ai, bv[j4].w, acc[i][j4 * 4 + 3]);
                }
            }
        }
        __syncthreads();
    }

#pragma unroll
    for (int i = 0; i < TM; ++i) {
        int grow = block_row + ty * TM + i;
        if (grow < M) {
#pragma unroll
            for (int j4 = 0; j4 < TN / 4; ++j4) {
                float4 v = {acc[i][j4 * 4 + 0], acc[i][j4 * 4 + 1],
                            acc[i][j4 * 4 + 2], acc[i][j4 * 4 + 3]};
                *(float4*)&Cout[(size_t)grow * NDIM + col_base + tx * 4 +
                                j4 * (BN / 2)] = v;
            }
        }
    }
}

template <int C, bool RELU>
__global__ void epilogue_kernel(const float* __restrict__ agg,
                                const float* __restrict__ h,
                                const float* __restrict__ dinv,
                                const float* __restrict__ bias,
                                float* __restrict__ out, int N) {
    int tid = blockIdx.x * blockDim.x + threadIdx.x;
    int total = N * (C / 4);
    if (tid >= total) return;
    int c4  = tid % (C / 4);
    int row = tid / (C / 4);
    float d2 = dinv[row];
    d2 *= d2;
    float4 a  = *(const float4*)&agg[(size_t)tid * 4];
    float4 hv = *(const float4*)&h[(size_t)tid * 4];
    float4 b  = *(const float4*)&bias[c4 * 4];
    float4 r;
    r.x = a.x + hv.x * d2 + b.x;
    r.y = a.y + hv.y * d2 + b.y;
    r.z = a.z + hv.z * d2 + b.z;
    r.w = a.w + hv.w * d2 + b.w;
    if (RELU) {
        r.x = fmaxf(r.x, 0.f);
        r.y = fmaxf(r.y, 0.f);
        r.z = fmaxf(r.z, 0.f);
        r.w = fmaxf(r.w, 0.f);
    }
    *(float4*)&out[(size_t)tid * 4] = r;
}

// ---------------------------------------------------------------- launch ---
extern "C" void kernel_launch(void* const* d_in, const int* in_sizes, int n_in,
                              void* d_out, int out_size, void* d_ws, size_t ws_size,
                              hipStream_t stream) {
    const float* x   = (const float*)d_in[0];
    const int*   ei  = (const int*)d_in[1];
    const float* W1  = (const float*)d_in[2];
    const float* b1  = (const float*)d_in[3];
    const float* W2  = (const float*)d_in[4];
    const float* b2  = (const float*)d_in[5];
    float*       out = (float*)d_out;

    const int* src = ei;
    const int* dst = ei + N_EDGES;

    char* ws = (char*)d_ws;
    size_t off = 0;
    auto alloc = [&](size_t bytes) {
        void* p = ws + off;
        off += (bytes + 255) & ~(size_t)255;
        return p;
    };

    // --- CSR-gather path layout ---
    unsigned int*   cur    = (unsigned int*)alloc(N_NODES * sizeof(unsigned int));
    unsigned int*   bsum   = (unsigned int*)alloc(SCAN_NB * sizeof(unsigned int));
    float*          dinv   = (float*)alloc(N_NODES * sizeof(float));
    int*            esrc   = (int*)alloc((size_t)N_EDGES * sizeof(int));
    unsigned int*   gpairs = (unsigned int*)alloc((size_t)N_EDGES * 4);
    unsigned int*   bbase  = (unsigned int*)alloc((NBK + 1) * sizeof(unsigned int));
    unsigned int*   bcur   = (unsigned int*)alloc(NBK * sizeof(unsigned int));
    unsigned short* Wt1    = (unsigned short*)alloc((size_t)IN_C * HID_C * 2);
    unsigned short* Wt2    = (unsigned short*)alloc((size_t)HID_C * OUT_C * 2);
    unsigned short* h1     = (unsigned short*)alloc((size_t)N_NODES * HID_C * 2);
    unsigned short* g1     = (unsigned short*)alloc((size_t)N_NODES * HID_C * 2);
    unsigned short* h2     = h1;   // gemm2 output reuses h1 space
    size_t needed = off;

    if (ws_size >= needed) {
        hipMemsetAsync(cur, 0, N_NODES * sizeof(unsigned int), stream);

        deg_kernel<<<(N_EDGES + 255) / 256, 256, 0, stream>>>(
            src, dst, cur, N_EDGES, W1, W2, Wt1, Wt2);
        scan1_kernel<<<SCAN_NB, 256, 0, stream>>>(cur, bsum, dinv, N_NODES);
        scan2_kernel<<<SCAN_NB, 256, 0, stream>>>(cur, bsum, bcur, bbase,
                                                  N_NODES);

        // fused: gemm1 (h1 = bf16(dinv*(x@W1))) || edge partition (packed)
        fused_gemm_part_kernel<IN_C, HID_C>
            <<<3 * NPB, 256, 0, stream>>>(x, Wt1, dinv, h1, N_NODES,
                                          src, dst, bcur, gpairs, N_EDGES);
        fine_fill_kernel<<<NBK, 256, 0, stream>>>(gpairs, bbase, cur, esrc,
                                                  N_NODES);
        {
            int total = N_NODES * (HID_C / 4);
            gather_kernel<HID_C, true, true>
                <<<(total + 255) / 256, 256, 0, stream>>>(cur, esrc, dinv, h1,
                                                          b1, g1, N_NODES);
        }
        // layer 2: h2 = bf16(dinv*(g1@W2)), A already bf16
        mfma_gemm_kernel<HID_C, OUT_C, true>
            <<<(N_NODES + 63) / 64, 256, 0, stream>>>(g1, Wt2, dinv, h2,
                                                      N_NODES);
        {
            int total = N_NODES * (OUT_C / 4);
            gather_kernel<OUT_C, false, false>
                <<<(total + 255) / 256, 256, 0, stream>>>(cur, esrc, dinv, h2,
                                                          b2, out, N_NODES);
        }
    } else {
        // ---------------- fallback: proven atomic-scatter path --------------
        off = 0;
        unsigned int* deg   = (unsigned int*)alloc(N_NODES * sizeof(unsigned int));
        float*        dinvF = (float*)alloc(N_NODES * sizeof(float));
        float*        h1F   = (float*)alloc((size_t)N_NODES * HID_C * sizeof(float));
        float*        agg1  = (float*)alloc((size_t)N_NODES * HID_C * sizeof(float));
        float*        h2F   = h1F;

        hipMemsetAsync(deg, 0, N_NODES * sizeof(unsigned int), stream);
        hipMemsetAsync(agg1, 0, (size_t)N_NODES * HID_C * sizeof(float), stream);
        hipMemsetAsync(out, 0, (size_t)N_NODES * OUT_C * sizeof(float), stream);

        deg_kernel<<<(N_EDGES + 255) / 256, 256, 0, stream>>>(
            src, dst, deg, N_EDGES, nullptr, nullptr, nullptr, nullptr);
        dinv_only_kernel<<<(N_NODES + 255) / 256, 256, 0, stream>>>(deg, dinvF,
                                                                    N_NODES);

        gemm_kernel<64, 64, 16, 4, 4, IN_C, HID_C>
            <<<dim3((N_NODES + 63) / 64, HID_C / 64), 256, 0, stream>>>(
                x, W1, h1F, N_NODES);
        {
            long long total = (long long)N_EDGES * (HID_C / 4);
            scatter_kernel<HID_C, HID_C / 4>
                <<<(unsigned)((total + 255) / 256), 256, 0, stream>>>(
                    src, dst, dinvF, h1F, agg1, N_EDGES);
        }
        {
            int total = N_NODES * (HID_C / 4);
            epilogue_kernel<HID_C, true>
                <<<(total + 255) / 256, 256, 0, stream>>>(agg1, h1F, dinvF, b1,
                                                          agg1, N_NODES);
        }
        gemm_kernel<64, 64, 16, 4, 4, HID_C, OUT_C>
            <<<dim3((N_NODES + 63) / 64, OUT_C / 64), 256, 0, stream>>>(
                agg1, W2, h2F, N_NODES);
        {
            long long total = (long long)N_EDGES * (OUT_C / 4);
            scatter_kernel<OUT_C, OUT_C / 4>
                <<<(unsigned)((total + 255) / 256), 256, 0, stream>>>(
                    src, dst, dinvF, h2F, out, N_EDGES);
        }
        {
            int total = N_NODES * (OUT_C / 4);
            epilogue_kernel<OUT_C, false>
                <<<(total + 255) / 256, 256, 0, stream>>>(out, h2F, dinvF, b2,
                                                          out, N_NODES);
        }
    }
}

// Round 16
// 147.067 us; speedup vs baseline: 1.1535x; 1.0040x over previous
//
#include <hip/hip_runtime.h>

#define N_NODES 50000
#define N_EDGES 800000
#define IN_C    256
#define HID_C   128
#define OUT_C   64

#define SCAN_CHUNK 512
#define SCAN_NB ((N_NODES + SCAN_CHUNK - 1) / SCAN_CHUNK)   // 98

#define NBK 391          // ceil(N_NODES/128) buckets of 128 nodes
#define PCH 2048         // edges per partition block
#define NPB ((N_EDGES + PCH - 1) / PCH)                      // 391

typedef __attribute__((ext_vector_type(8))) __bf16 bf16x8;
typedef __attribute__((ext_vector_type(4))) float f32x4;

// ----------------------------------------------------------- bf16 helpers --
__device__ __forceinline__ unsigned short f2bf(float f) {
    union { float f; unsigned int u; } c{f};
    unsigned int r = c.u + 0x7FFFu + ((c.u >> 16) & 1u);   // RNE
    return (unsigned short)(r >> 16);
}
__device__ __forceinline__ float bf2f(unsigned short b) {
    union { unsigned int u; float f; } c{(unsigned int)b << 16};
    return c.f;
}

// ------------------------------------------------------------------ zero ---
// Replaces hipMemsetAsync(cur): the runtime's fillBufferAligned ran this
// 200 KB fill at ~40 us (8% occupancy). One uint4 store per thread: ~2 us.
__global__ void zero_kernel(uint4* __restrict__ p, int n4) {
    int i = blockIdx.x * blockDim.x + threadIdx.x;
    if (i < n4) p[i] = uint4{0u, 0u, 0u, 0u};
}

// --------------------------------------------- degree + W bf16-transpose ---
__global__ void deg_kernel(const int* __restrict__ src,
                           const int* __restrict__ dst,
                           unsigned int* __restrict__ deg, int E,
                           const float* __restrict__ W1,
                           const float* __restrict__ W2,
                           unsigned short* __restrict__ Wt1,
                           unsigned short* __restrict__ Wt2) {
    const int bid = blockIdx.x;
    const int t   = threadIdx.x;
    if (Wt1 != nullptr && bid < 40) {
        if (bid < 32) {               // W1: 256x128
            int e = bid * 1024 + t * 4;
            float4 v = *(const float4*)&W1[e];
            int k = e >> 7, c = e & 127;
            Wt1[(c + 0) * IN_C + k] = f2bf(v.x);
            Wt1[(c + 1) * IN_C + k] = f2bf(v.y);
            Wt1[(c + 2) * IN_C + k] = f2bf(v.z);
            Wt1[(c + 3) * IN_C + k] = f2bf(v.w);
        } else {                      // W2: 128x64
            int e = (bid - 32) * 1024 + t * 4;
            float4 v = *(const float4*)&W2[e];
            int k = e >> 6, c = e & 63;
            Wt2[(c + 0) * HID_C + k] = f2bf(v.x);
            Wt2[(c + 1) * HID_C + k] = f2bf(v.y);
            Wt2[(c + 2) * HID_C + k] = f2bf(v.z);
            Wt2[(c + 3) * HID_C + k] = f2bf(v.w);
        }
    }
    int i = bid * blockDim.x + t;
    if (i < E) {
        int s = src[i];
        int d = dst[i];
        if ((unsigned)s < N_NODES && (unsigned)d < N_NODES)
            atomicAdd(&deg[d], 1u);
    }
}

// ------------------------------------------------------------------ scan ---
__global__ __launch_bounds__(256) void scan1_kernel(
        unsigned int* __restrict__ cur, unsigned int* __restrict__ bsum,
        float* __restrict__ dinv, int N) {
    __shared__ unsigned int lds[256];
    const int b = blockIdx.x;
    const int t = threadIdx.x;
    const int i0 = b * SCAN_CHUNK + 2 * t;

    unsigned e0 = (i0     < N) ? cur[i0]     : 0u;
    unsigned e1 = (i0 + 1 < N) ? cur[i0 + 1] : 0u;
    if (i0     < N) dinv[i0]     = rsqrtf((float)(e0 + 1u));
    if (i0 + 1 < N) dinv[i0 + 1] = rsqrtf((float)(e1 + 1u));

    unsigned p = e0 + e1;
    lds[t] = p;
    __syncthreads();
    for (int off = 1; off < 256; off <<= 1) {
        unsigned v = (t >= off) ? lds[t - off] : 0u;
        __syncthreads();
        lds[t] += v;
        __syncthreads();
    }
    unsigned excl = lds[t] - p;
    if (t == 255) bsum[b] = lds[255];
    if (i0     < N) cur[i0]     = excl;
    if (i0 + 1 < N) cur[i0 + 1] = excl + e0;
}

// scan2 also emits bucket bases/cursors (binit fused).
__global__ __launch_bounds__(256) void scan2_kernel(
        unsigned int* __restrict__ cur, const unsigned int* __restrict__ bsum,
        unsigned int* __restrict__ bcur, unsigned int* __restrict__ bbase,
        int N) {
    __shared__ unsigned int lds[256];
    const int b = blockIdx.x;
    const int t = threadIdx.x;
    lds[t] = (t < b && t < SCAN_NB) ? bsum[t] : 0u;
    __syncthreads();
    for (int off = 128; off > 0; off >>= 1) {
        if (t < off) lds[t] += lds[t + off];
        __syncthreads();
    }
    const unsigned offset = lds[0];
    const int i0 = b * SCAN_CHUNK + 2 * t;
    if (i0 < N) {
        unsigned v0 = cur[i0] + offset;
        cur[i0] = v0;
        if ((i0 & 127) == 0) {           // bucket boundary: snapshot start
            bcur[i0 >> 7]  = v0;
            bbase[i0 >> 7] = v0;
        }
    }
    if (i0 + 1 < N) cur[i0 + 1] += offset;
    if (b == 0 && t == 0) bbase[NBK] = N_EDGES;
}

// ----------------------------------------- fused gemm1 || edge partition ---
template <int KDIM, int NDIM>
__global__ __launch_bounds__(256) void fused_gemm_part_kernel(
        const float* __restrict__ A, const unsigned short* __restrict__ Wt,
        const float* __restrict__ dinv,
        unsigned short* __restrict__ Cout, int M,
        const int* __restrict__ src, const int* __restrict__ dst,
        unsigned int* __restrict__ bcur,
        unsigned int* __restrict__ gpairs, int E) {
    __shared__ union {
        struct { unsigned short A[64][40]; unsigned short B[NDIM][40]; } g;
        struct { unsigned int pairs[PCH];
                 unsigned int counts[512];
                 unsigned int starts[513];
                 unsigned int gbase[NBK];
                 unsigned int temp[256]; } p;
    } sh;

    const int bid  = blockIdx.x;
    const int t    = threadIdx.x;
    const int role = bid % 3;
    const int pb   = bid / 3;

    if (role == 2) {
        // --------------------------- partition -----------------------------
        const int base = pb * PCH;
        for (int i = t; i < 512; i += 256) sh.p.counts[i] = 0;
        __syncthreads();

        unsigned preg[PCH / 256], rreg[PCH / 256];
        bool val[PCH / 256];
#pragma unroll
        for (int j = 0; j < PCH / 256; ++j) {
            int i = base + j * 256 + t;
            val[j] = false;
            if (i < E) {
                int s = src[i], d = dst[i];
                if ((unsigned)s < N_NODES && (unsigned)d < N_NODES) {
                    val[j] = true;
                    unsigned bkt = (unsigned)d >> 7;
                    preg[j] = (bkt << 23) | (((unsigned)d & 127u) << 16) |
                              (unsigned)s;
                    rreg[j] = atomicAdd(&sh.p.counts[bkt], 1u);
                }
            }
        }
        __syncthreads();
        unsigned e0 = sh.p.counts[2 * t], e1 = sh.p.counts[2 * t + 1];
        unsigned pp = e0 + e1;
        sh.p.temp[t] = pp;
        __syncthreads();
        for (int off = 1; off < 256; off <<= 1) {
            unsigned v = (t >= off) ? sh.p.temp[t - off] : 0u;
            __syncthreads();
            sh.p.temp[t] += v;
            __syncthreads();
        }
        unsigned excl = sh.p.temp[t] - pp;
        sh.p.starts[2 * t]     = excl;
        sh.p.starts[2 * t + 1] = excl + e0;
        if (t == 255) sh.p.starts[512] = sh.p.temp[255];
        __syncthreads();
        for (int b = t; b < NBK; b += 256) {
            unsigned c = sh.p.counts[b];
            if (c) sh.p.gbase[b] = atomicAdd(&bcur[b], c);
        }
        __syncthreads();
#pragma unroll
        for (int j = 0; j < PCH / 256; ++j)
            if (val[j]) {
                unsigned bkt  = preg[j] >> 23;
                unsigned slot = sh.p.starts[bkt] + rreg[j];
                sh.p.pairs[slot] = preg[j];
            }
        __syncthreads();
        unsigned total = sh.p.starts[512];
        for (unsigned i = t; i < total; i += 256) {
            unsigned pd  = sh.p.pairs[i];
            unsigned bkt = pd >> 23;
            unsigned rank = i - sh.p.starts[bkt];
            gpairs[sh.p.gbase[bkt] + rank] = pd;
        }
        return;
    }

    // ------------------------------ gemm role ------------------------------
    const int gb = pb * 2 + role;
    if (gb >= (M + 63) / 64) return;
    constexpr int NF = NDIM / 16;
    const int block_row = gb * 64;
    const int w    = t >> 6;
    const int lane = t & 63;
    const int arow = lane & 15;
    const int g    = lane >> 4;

    f32x4 acc[NF] = {};

    for (int k0 = 0; k0 < KDIM; k0 += 32) {
#pragma unroll
        for (int q = 0; q < 2; ++q) {
            int u   = t * 2 + q;
            int row = u >> 3;
            int kq  = u & 7;
            int grow = block_row + row;
            if (grow >= M) grow = M - 1;
            float4 v = *(const float4*)&A[(size_t)grow * KDIM + k0 + kq * 4];
            ushort4 bb = {f2bf(v.x), f2bf(v.y), f2bf(v.z), f2bf(v.w)};
            *(ushort4*)&sh.g.A[row][kq * 4] = bb;
        }
        {
            constexpr int B8 = (NDIM * 4) / 256;   // uint4 units per thread
#pragma unroll
            for (int r = 0; r < B8; ++r) {
                int iu  = t * B8 + r;
                int col = iu >> 2;
                int k8  = iu & 3;
                *(uint4*)&sh.g.B[col][k8 * 8] =
                    *(const uint4*)&Wt[(size_t)col * KDIM + k0 + k8 * 8];
            }
        }
        __syncthreads();

        bf16x8 af = *(const bf16x8*)&sh.g.A[w * 16 + arow][g * 8];
#pragma unroll
        for (int f = 0; f < NF; ++f) {
            bf16x8 bf_ = *(const bf16x8*)&sh.g.B[f * 16 + arow][g * 8];
            acc[f] = __builtin_amdgcn_mfma_f32_16x16x32_bf16(af, bf_, acc[f],
                                                             0, 0, 0);
        }
        __syncthreads();
    }

#pragma unroll
    for (int i = 0; i < 4; ++i) {
        int row = block_row + w * 16 + g * 4 + i;
        if (row < M) {
            float dv = dinv[row];
#pragma unroll
            for (int f = 0; f < NF; ++f)
                Cout[(size_t)row * NDIM + f * 16 + arow] = f2bf(dv * acc[f][i]);
        }
    }
}

// ------------------------------------------------------------- fine fill ---
__global__ __launch_bounds__(256) void fine_fill_kernel(
        const unsigned int* __restrict__ gpairs,
        const unsigned int* __restrict__ bbase,
        unsigned int* __restrict__ cur,
        int* __restrict__ esrc, int N) {
    __shared__ unsigned int cnt[128];
    __shared__ unsigned int inc[128];
    const int b  = blockIdx.x;
    const int t  = threadIdx.x;
    const unsigned e0 = bbase[b], e1 = bbase[b + 1];
    const int node0 = b << 7;
    const int nn = min(128, N - node0);

    if (t < 128) cnt[t] = 0;
    __syncthreads();
    for (unsigned i = e0 + t; i < e1; i += 256) {
        unsigned dloc = (gpairs[i] >> 16) & 127u;
        atomicAdd(&cnt[dloc], 1u);
    }
    __syncthreads();
    if (t < 128) inc[t] = cnt[t];
    __syncthreads();
    for (int off = 1; off < 128; off <<= 1) {
        unsigned a = (t >= off && t < 128) ? inc[t - off] : 0u;
        __syncthreads();
        if (t < 128) inc[t] += a;
        __syncthreads();
    }
    if (t < 128) cnt[t] = inc[t] - cnt[t];
    __syncthreads();
    for (unsigned i = e0 + t; i < e1; i += 256) {
        unsigned pd   = gpairs[i];
        unsigned dloc = (pd >> 16) & 127u;
        unsigned r = atomicAdd(&cnt[dloc], 1u);
        esrc[e0 + r] = (int)(pd & 0xFFFFu);
    }
    __syncthreads();
    if (t < nn) cur[node0 + t] = e0 + inc[t];   // end(v)
}

// ------------------------------------------------ standalone MFMA GEMM -----
template <int KDIM, int NDIM, bool ABF16>
__global__ __launch_bounds__(256) void mfma_gemm_kernel(
        const void* __restrict__ Ain, const unsigned short* __restrict__ Wt,
        const float* __restrict__ dinv,
        unsigned short* __restrict__ Cout, int M) {
    __shared__ unsigned short Alds[64][40];
    __shared__ unsigned short Blds[NDIM][40];

    const int t = threadIdx.x;
    constexpr int NF = NDIM / 16;
    const int block_row = blockIdx.x * 64;
    const int w    = t >> 6;
    const int lane = t & 63;
    const int arow = lane & 15;
    const int g    = lane >> 4;

    f32x4 acc[NF] = {};

    for (int k0 = 0; k0 < KDIM; k0 += 32) {
        if (ABF16) {
            const unsigned short* A = (const unsigned short*)Ain;
            int row = t >> 2;
            int k8  = t & 3;
            int grow = block_row + row;
            if (grow >= M) grow = M - 1;
            *(uint4*)&Alds[row][k8 * 8] =
                *(const uint4*)&A[(size_t)grow * KDIM + k0 + k8 * 8];
        } else {
            const float* A = (const float*)Ain;
#pragma unroll
            for (int q = 0; q < 2; ++q) {
                int u   = t * 2 + q;
                int row = u >> 3;
                int kq  = u & 7;
                int grow = block_row + row;
                if (grow >= M) grow = M - 1;
                float4 v = *(const float4*)&A[(size_t)grow * KDIM + k0 + kq * 4];
                ushort4 bb = {f2bf(v.x), f2bf(v.y), f2bf(v.z), f2bf(v.w)};
                *(ushort4*)&Alds[row][kq * 4] = bb;
            }
        }
        {
            constexpr int B8 = (NDIM * 4) / 256;
#pragma unroll
            for (int r = 0; r < B8; ++r) {
                int iu  = t * B8 + r;
                int col = iu >> 2;
                int k8  = iu & 3;
                *(uint4*)&Blds[col][k8 * 8] =
                    *(const uint4*)&Wt[(size_t)col * KDIM + k0 + k8 * 8];
            }
        }
        __syncthreads();

        bf16x8 af = *(const bf16x8*)&Alds[w * 16 + arow][g * 8];
#pragma unroll
        for (int f = 0; f < NF; ++f) {
            bf16x8 bf_ = *(const bf16x8*)&Blds[f * 16 + arow][g * 8];
            acc[f] = __builtin_amdgcn_mfma_f32_16x16x32_bf16(af, bf_, acc[f],
                                                             0, 0, 0);
        }
        __syncthreads();
    }

#pragma unroll
    for (int i = 0; i < 4; ++i) {
        int row = block_row + w * 16 + g * 4 + i;
        if (row < M) {
            float dv = dinv[row];
#pragma unroll
            for (int f = 0; f < NF; ++f)
                Cout[(size_t)row * NDIM + f * 16 + arow] = f2bf(dv * acc[f][i]);
        }
    }
}

// ---------------------------------------------------------------- gather ---
template <int C, bool RELU, bool OUTBF16>
__global__ __launch_bounds__(256) void gather_kernel(
        const unsigned int* __restrict__ cur,   // ends
        const int* __restrict__ esrc,
        const float* __restrict__ dinv,
        const unsigned short* __restrict__ h,   // bf16, pre-scaled by dinv
        const float* __restrict__ bias,
        void* __restrict__ out, int N) {
    constexpr int G = C / 4;
    int tid  = blockIdx.x * blockDim.x + threadIdx.x;
    int v    = tid / G;
    int lane = tid % G;
    if (v >= N) return;
    unsigned int start = (v == 0) ? 0u : cur[v - 1];
    unsigned int end   = cur[v];

    ushort4 hs = *(const ushort4*)&h[(size_t)v * C + lane * 4];
    float4 a0 = {bf2f(hs.x), bf2f(hs.y), bf2f(hs.z), bf2f(hs.w)};
    float4 a1 = {0.f, 0.f, 0.f, 0.f};
    float4 a2 = {0.f, 0.f, 0.f, 0.f};
    float4 a3 = {0.f, 0.f, 0.f, 0.f};

    unsigned int e = start;
    for (; e + 4 <= end; e += 4) {
        int s0 = esrc[e + 0];
        int s1 = esrc[e + 1];
        int s2 = esrc[e + 2];
        int s3 = esrc[e + 3];
        ushort4 v0 = *(const ushort4*)&h[(size_t)s0 * C + lane * 4];
        ushort4 v1 = *(const ushort4*)&h[(size_t)s1 * C + lane * 4];
        ushort4 v2 = *(const ushort4*)&h[(size_t)s2 * C + lane * 4];
        ushort4 v3 = *(const ushort4*)&h[(size_t)s3 * C + lane * 4];
        a0.x += bf2f(v0.x); a0.y += bf2f(v0.y); a0.z += bf2f(v0.z); a0.w += bf2f(v0.w);
        a1.x += bf2f(v1.x); a1.y += bf2f(v1.y); a1.z += bf2f(v1.z); a1.w += bf2f(v1.w);
        a2.x += bf2f(v2.x); a2.y += bf2f(v2.y); a2.z += bf2f(v2.z); a2.w += bf2f(v2.w);
        a3.x += bf2f(v3.x); a3.y += bf2f(v3.y); a3.z += bf2f(v3.z); a3.w += bf2f(v3.w);
    }
    for (; e < end; ++e) {
        int s = esrc[e];
        ushort4 v0 = *(const ushort4*)&h[(size_t)s * C + lane * 4];
        a0.x += bf2f(v0.x); a0.y += bf2f(v0.y); a0.z += bf2f(v0.z); a0.w += bf2f(v0.w);
    }
    float4 acc;
    acc.x = (a0.x + a1.x) + (a2.x + a3.x);
    acc.y = (a0.y + a1.y) + (a2.y + a3.y);
    acc.z = (a0.z + a1.z) + (a2.z + a3.z);
    acc.w = (a0.w + a1.w) + (a2.w + a3.w);

    float dv = dinv[v];
    float4 b = *(const float4*)&bias[lane * 4];
    float4 r;
    r.x = fmaf(dv, acc.x, b.x);
    r.y = fmaf(dv, acc.y, b.y);
    r.z = fmaf(dv, acc.z, b.z);
    r.w = fmaf(dv, acc.w, b.w);
    if (RELU) {
        r.x = fmaxf(r.x, 0.f);
        r.y = fmaxf(r.y, 0.f);
        r.z = fmaxf(r.z, 0.f);
        r.w = fmaxf(r.w, 0.f);
    }
    if (OUTBF16) {
        ushort4 o = {f2bf(r.x), f2bf(r.y), f2bf(r.z), f2bf(r.w)};
        *(ushort4*)&((unsigned short*)out)[(size_t)v * C + lane * 4] = o;
    } else {
        *(float4*)&((float*)out)[(size_t)v * C + lane * 4] = r;
    }
}

// ------------------------------------------- fallback path (atomics) ------
template <int C, int C4>
__global__ void scatter_kernel(const int* __restrict__ src,
                               const int* __restrict__ dst,
                               const float* __restrict__ dinv,
                               const float* __restrict__ h,
                               float* __restrict__ out, int E) {
    int tid  = blockIdx.x * blockDim.x + threadIdx.x;
    int e    = tid / C4;
    int lane = tid % C4;
    if (e >= E) return;
    int s = src[e];
    int d = dst[e];
    if ((unsigned)s >= N_NODES || (unsigned)d >= N_NODES) return;
    float norm = dinv[s] * dinv[d];
    float4 v = *(const float4*)&h[(size_t)s * C + lane * 4];
    float* o = &out[(size_t)d * C + lane * 4];
    unsafeAtomicAdd(o + 0, v.x * norm);
    unsafeAtomicAdd(o + 1, v.y * norm);
    unsafeAtomicAdd(o + 2, v.z * norm);
    unsafeAtomicAdd(o + 3, v.w * norm);
}

__global__ void dinv_only_kernel(const unsigned int* __restrict__ deg,
                                 float* __restrict__ dinv, int N) {
    int i = blockIdx.x * blockDim.x + threadIdx.x;
    if (i < N) dinv[i] = rsqrtf((float)(deg[i] + 1u));
}

template <int BM, int BN, int BK, int TM, int TN, int KDIM, int NDIM>
__global__ __launch_bounds__(256) void gemm_kernel(
        const float* __restrict__ A, const float* __restrict__ B,
        float* __restrict__ Cout, int M) {
    __shared__ float As[BK][BM + 1];
    __shared__ float Bs[BK][BN];

    constexpr int TX = BN / TN;
    const int t  = threadIdx.x;
    const int tx = t % TX;
    const int ty = t / TX;
    const int block_row = blockIdx.x * BM;
    const int col_base  = blockIdx.y * BN;

    float acc[TM][TN] = {};

    for (int k0 = 0; k0 < KDIM; k0 += BK) {
        for (int i = t; i < BM * BK / 4; i += 256) {
            int row = i / (BK / 4);
            int c4  = i % (BK / 4);
            int grow = block_row + row;
            if (grow >= M) grow = M - 1;
            float4 v = *(const float4*)&A[(size_t)grow * KDIM + k0 + c4 * 4];
            As[c4 * 4 + 0][row] = v.x;
            As[c4 * 4 + 1][row] = v.y;
            As[c4 * 4 + 2][row] = v.z;
            As[c4 * 4 + 3][row] = v.w;
        }
        for (int i = t; i < BK * BN / 4; i += 256) {
            int row = i / (BN / 4);
            int c4  = i % (BN / 4);
            *(float4*)&Bs[row][c4 * 4] =
                *(const float4*)&B[(size_t)(k0 + row) * NDIM + col_base + c4 * 4];
        }
        __syncthreads();

#pragma unroll
        for (int kk = 0; kk < BK; ++kk) {
            float4 av = *(const float4*)&As[kk][ty * TM];
            float a_[4] = {av.x, av.y, av.z, av.w};
            float4 bv[TN / 4];
#pragma unroll
            for (int j4 = 0; j4 < TN / 4; ++j4)
                bv[j4] = *(const float4*)&Bs[kk][tx * 4 + j4 * (BN / 2)];
#pragma unroll
            for (int i = 0; i < TM; ++i) {
                float ai = a_[i];
#pragma unroll
                for (int j4 = 0; j4 < TN / 4; ++j4) {
                    acc[i][j4 * 4 + 0] = fmaf(ai, bv[j4].x, acc[i][j4 * 4 + 0]);
                    acc[i][j4 * 4 + 1] = fmaf(ai, bv[j4].y, acc[i][j4 * 4 + 1]);
                    acc[i][j4 * 4 + 2] = fmaf(ai, bv[j4].z, acc[i][j4 * 4 + 2]);
                    acc[i][j4 * 4 + 3] = fmaf(ai, bv[j4].w, acc[i][j4 * 4 + 3]);
                }
            }
        }
        __syncthreads();
    }

#pragma unroll
    for (int i = 0; i < TM; ++i) {
        int grow = block_row + ty * TM + i;
        if (grow < M) {
#pragma unroll
            for (int j4 = 0; j4 < TN / 4; ++j4) {
                float4 v = {acc[i][j4 * 4 + 0], acc[i][j4 * 4 + 1],
                            acc[i][j4 * 4 + 2], acc[i][j4 * 4 + 3]};
                *(float4*)&Cout[(size_t)grow * NDIM + col_base + tx * 4 +
                                j4 * (BN / 2)] = v;
            }
        }
    }
}

template <int C, bool RELU>
__global__ void epilogue_kernel(const float* __restrict__ agg,
                                const float* __restrict__ h,
                                const float* __restrict__ dinv,
                                const float* __restrict__ bias,
                                float* __restrict__ out, int N) {
    int tid = blockIdx.x * blockDim.x + threadIdx.x;
    int total = N * (C / 4);
    if (tid >= total) return;
    int c4  = tid % (C / 4);
    int row = tid / (C / 4);
    float d2 = dinv[row];
    d2 *= d2;
    float4 a  = *(const float4*)&agg[(size_t)tid * 4];
    float4 hv = *(const float4*)&h[(size_t)tid * 4];
    float4 b  = *(const float4*)&bias[c4 * 4];
    float4 r;
    r.x = a.x + hv.x * d2 + b.x;
    r.y = a.y + hv.y * d2 + b.y;
    r.z = a.z + hv.z * d2 + b.z;
    r.w = a.w + hv.w * d2 + b.w;
    if (RELU) {
        r.x = fmaxf(r.x, 0.f);
        r.y = fmaxf(r.y, 0.f);
        r.z = fmaxf(r.z, 0.f);
        r.w = fmaxf(r.w, 0.f);
    }
    *(float4*)&out[(size_t)tid * 4] = r;
}

// ---------------------------------------------------------------- launch ---
extern "C" void kernel_launch(void* const* d_in, const int* in_sizes, int n_in,
                              void* d_out, int out_size, void* d_ws, size_t ws_size,
                              hipStream_t stream) {
    const float* x   = (const float*)d_in[0];
    const int*   ei  = (const int*)d_in[1];
    const float* W1  = (const float*)d_in[2];
    const float* b1  = (const float*)d_in[3];
    const float* W2  = (const float*)d_in[4];
    const float* b2  = (const float*)d_in[5];
    float*       out = (float*)d_out;

    const int* src = ei;
    const int* dst = ei + N_EDGES;

    char* ws = (char*)d_ws;
    size_t off = 0;
    auto alloc = [&](size_t bytes) {
        void* p = ws + off;
        off += (bytes + 255) & ~(size_t)255;
        return p;
    };

    // --- CSR-gather path layout ---
    unsigned int*   cur    = (unsigned int*)alloc(N_NODES * sizeof(unsigned int));
    unsigned int*   bsum   = (unsigned int*)alloc(SCAN_NB * sizeof(unsigned int));
    float*          dinv   = (float*)alloc(N_NODES * sizeof(float));
    int*            esrc   = (int*)alloc((size_t)N_EDGES * sizeof(int));
    unsigned int*   gpairs = (unsigned int*)alloc((size_t)N_EDGES * 4);
    unsigned int*   bbase  = (unsigned int*)alloc((NBK + 1) * sizeof(unsigned int));
    unsigned int*   bcur   = (unsigned int*)alloc(NBK * sizeof(unsigned int));
    unsigned short* Wt1    = (unsigned short*)alloc((size_t)IN_C * HID_C * 2);
    unsigned short* Wt2    = (unsigned short*)alloc((size_t)HID_C * OUT_C * 2);
    unsigned short* h1     = (unsigned short*)alloc((size_t)N_NODES * HID_C * 2);
    unsigned short* g1     = (unsigned short*)alloc((size_t)N_NODES * HID_C * 2);
    unsigned short* h2     = h1;   // gemm2 output reuses h1 space
    size_t needed = off;

    if (ws_size >= needed) {
        // fast zero of cur (replaces ~40us runtime fillBufferAligned)
        {
            int n4 = (N_NODES * 4) / 16;                 // 12500 uint4
            zero_kernel<<<(n4 + 255) / 256, 256, 0, stream>>>((uint4*)cur, n4);
        }

        deg_kernel<<<(N_EDGES + 255) / 256, 256, 0, stream>>>(
            src, dst, cur, N_EDGES, W1, W2, Wt1, Wt2);
        scan1_kernel<<<SCAN_NB, 256, 0, stream>>>(cur, bsum, dinv, N_NODES);
        scan2_kernel<<<SCAN_NB, 256, 0, stream>>>(cur, bsum, bcur, bbase,
                                                  N_NODES);

        // fused: gemm1 (h1 = bf16(dinv*(x@W1))) || edge partition (packed)
        fused_gemm_part_kernel<IN_C, HID_C>
            <<<3 * NPB, 256, 0, stream>>>(x, Wt1, dinv, h1, N_NODES,
                                          src, dst, bcur, gpairs, N_EDGES);
        fine_fill_kernel<<<NBK, 256, 0, stream>>>(gpairs, bbase, cur, esrc,
                                                  N_NODES);
        {
            int total = N_NODES * (HID_C / 4);
            gather_kernel<HID_C, true, true>
                <<<(total + 255) / 256, 256, 0, stream>>>(cur, esrc, dinv, h1,
                                                          b1, g1, N_NODES);
        }
        // layer 2: h2 = bf16(dinv*(g1@W2)), A already bf16
        mfma_gemm_kernel<HID_C, OUT_C, true>
            <<<(N_NODES + 63) / 64, 256, 0, stream>>>(g1, Wt2, dinv, h2,
                                                      N_NODES);
        {
            int total = N_NODES * (OUT_C / 4);
            gather_kernel<OUT_C, false, false>
                <<<(total + 255) / 256, 256, 0, stream>>>(cur, esrc, dinv, h2,
                                                          b2, out, N_NODES);
        }
    } else {
        // ---------------- fallback: proven atomic-scatter path --------------
        off = 0;
        unsigned int* deg   = (unsigned int*)alloc(N_NODES * sizeof(unsigned int));
        float*        dinvF = (float*)alloc(N_NODES * sizeof(float));
        float*        h1F   = (float*)alloc((size_t)N_NODES * HID_C * sizeof(float));
        float*        agg1  = (float*)alloc((size_t)N_NODES * HID_C * sizeof(float));
        float*        h2F   = h1F;

        hipMemsetAsync(deg, 0, N_NODES * sizeof(unsigned int), stream);
        hipMemsetAsync(agg1, 0, (size_t)N_NODES * HID_C * sizeof(float), stream);
        hipMemsetAsync(out, 0, (size_t)N_NODES * OUT_C * sizeof(float), stream);

        deg_kernel<<<(N_EDGES + 255) / 256, 256, 0, stream>>>(
            src, dst, deg, N_EDGES, nullptr, nullptr, nullptr, nullptr);
        dinv_only_kernel<<<(N_NODES + 255) / 256, 256, 0, stream>>>(deg, dinvF,
                                                                    N_NODES);

        gemm_kernel<64, 64, 16, 4, 4, IN_C, HID_C>
            <<<dim3((N_NODES + 63) / 64, HID_C / 64), 256, 0, stream>>>(
                x, W1, h1F, N_NODES);
        {
            long long total = (long long)N_EDGES * (HID_C / 4);
            scatter_kernel<HID_C, HID_C / 4>
                <<<(unsigned)((total + 255) / 256), 256, 0, stream>>>(
                    src, dst, dinvF, h1F, agg1, N_EDGES);
        }
        {
            int total = N_NODES * (HID_C / 4);
            epilogue_kernel<HID_C, true>
                <<<(total + 255) / 256, 256, 0, stream>>>(agg1, h1F, dinvF, b1,
                                                          agg1, N_NODES);
        }
        gemm_kernel<64, 64, 16, 4, 4, HID_C, OUT_C>
            <<<dim3((N_NODES + 63) / 64, OUT_C / 64), 256, 0, stream>>>(
                agg1, W2, h2F, N_NODES);
        {
            long long total = (long long)N_EDGES * (OUT_C / 4);
            scatter_kernel<OUT_C, OUT_C / 4>
                <<<(unsigned)((total + 255) / 256), 256, 0, stream>>>(
                    src, dst, dinvF, h2F, out, N_EDGES);
        }
        {
            int total = N_NODES * (OUT_C / 4);
            epilogue_kernel<OUT_C, false>
                <<<(total + 255) / 256, 256, 0, stream>>>(out, h2F, dinvF, b2,
                                                          out, N_NODES);
        }
    }
}